// Round 10
// baseline (740.690 us; speedup 1.0000x reference)
//
#include <hip/hip_runtime.h>

typedef unsigned short ushort_t;
typedef unsigned int   uint32;
typedef __attribute__((ext_vector_type(8))) short short8;   // 8 bf16 (4 VGPRs)
typedef __attribute__((ext_vector_type(4))) float f32x4;    // MFMA acc
typedef __attribute__((ext_vector_type(4))) uint32 u32x4;

// ---------------- problem constants ----------------
#define B_     8
#define CIN    512
#define HFM    10
#define WFM    25
#define CF     64
#define NANCH  2784          // N
#define NANCHP 2816          // N padded to 64 (K-tiling)
#define NM     2783          // N-1
#define NMPAD  2816          // N-1 padded (cols for scores)
#define D_     640           // CF*HFM
#define D2     1280
#define ALEN   77
#define M_     (B_*NANCH)    // 22272
#define NO     128           // padded head-output dim (75 used)

#define VMCNT(N)   asm volatile("s_waitcnt vmcnt(" #N ")" ::: "memory")
#define S_BARRIER() do { __builtin_amdgcn_s_barrier(); __builtin_amdgcn_sched_barrier(0); } while (0)

__device__ __forceinline__ ushort_t f2bf(float f) {
    uint32 u = __float_as_uint(f);
    u += 0x7fffu + ((u >> 16) & 1u);     // RNE
    return (ushort_t)(u >> 16);
}
__device__ __forceinline__ float bf2f(ushort_t h) {
    return __uint_as_float(((uint32)h) << 16);
}

__device__ __forceinline__ void gload16(const ushort_t* g, ushort_t* l) {
    __builtin_amdgcn_global_load_lds(
        (const __attribute__((address_space(1))) void*)g,
        (__attribute__((address_space(3))) void*)l, 16, 0, 0);
}

// ============ 1x1 conv ============
__global__ __launch_bounds__(256) void conv_feat_k(const float* __restrict__ x,
    const float* __restrict__ w, const float* __restrict__ bias,
    float* __restrict__ feat)
{
    int t = blockIdx.x * 256 + threadIdx.x;
    if (t >= B_ * CF * HFM * WFM) return;
    int pos = t % (HFM * WFM);
    int f   = (t / (HFM * WFM)) % CF;
    int b   = t / (CF * HFM * WFM);
    const float* xp = x + (size_t)b * CIN * HFM * WFM + pos;
    const float* wp = w + (size_t)f * CIN;
    float s = bias[f];
#pragma unroll 4
    for (int c = 0; c < CIN; ++c)
        s += xp[(size_t)c * (HFM * WFM)] * wp[c];
    feat[t] = s;
}

// ============ gather -> pf16 [M_][640] ============
__global__ __launch_bounds__(256) void gather_pf_k(const float* __restrict__ feat,
    const int* __restrict__ cut_xs, const unsigned char* __restrict__ invalid,
    ushort_t* __restrict__ pf16)
{
    long long t = (long long)blockIdx.x * 256 + threadIdx.x;
    if (t >= (long long)M_ * D_) return;
    int d = (int)(t % D_);
    int r = (int)(t / D_);
    int n = r % NANCH;
    int b = r / NANCH;
    int f = d / HFM, h = d - f * HFM;
    int idx = n * HFM + h;
    float v = 0.f;
    if (!invalid[idx]) {
        int xs = cut_xs[idx];
        v = feat[((size_t)(b * CF + f) * HFM + h) * WFM + xs];
    }
    pf16[t] = f2bf(v);
}

// ============ attn_w fp32 [2783][640] -> bf16 padded [2816][640] ============
__global__ __launch_bounds__(256) void prep_attn_w_k(const float* __restrict__ attn_w,
    ushort_t* __restrict__ w16)
{
    int t = blockIdx.x * 256 + threadIdx.x;
    if (t >= NMPAD * D_) return;
    int m = t / D_;
    w16[t] = (m < NM) ? f2bf(attn_w[(size_t)m * D_ + (t % D_)]) : (ushort_t)0;
}

// ============ heads weights -> bf16 padded [128][1280] ============
__global__ __launch_bounds__(256) void prep_heads_w_k(const float* __restrict__ cls_w,
    const float* __restrict__ reg_w, ushort_t* __restrict__ w16)
{
    int t = blockIdx.x * 256 + threadIdx.x;
    if (t >= 128 * D2) return;
    int o = t / D2, k = t % D2;
    float v = 0.f;
    if (o < 2)       v = cls_w[(size_t)o * D2 + k];
    else if (o < 75) v = reg_w[(size_t)(o - 2) * D2 + k];
    w16[t] = (o < 75) ? f2bf(v) : (ushort_t)0;
}

// ============ zero Gt K-pad cols [2784..2816) ============
__global__ __launch_bounds__(256) void zero_gtpad_k(ushort_t* __restrict__ Gt)
{
    int t = blockIdx.x * 256 + threadIdx.x;
    if (t >= B_ * NO * 32) return;
    int n = t & 31, o = (t >> 5) & (NO - 1), b = t >> 12;
    Gt[((size_t)b * NO + o) * NANCHP + NANCH + n] = 0;
}

// ============ zero E diag + K-pad cols (scores never writes these) ============
__global__ __launch_bounds__(256) void zero_epad_k(ushort_t* __restrict__ E)
{
    int t = blockIdx.x * 256 + threadIdx.x;
    if (t < M_) {
        E[(size_t)t * NANCHP + (t % NANCH)] = 0;            // diagonal
    } else if (t < M_ * 17) {
        int idx = t - M_;
        int r = idx >> 4, w = idx & 15;
        *(uint32*)&E[(size_t)r * NANCHP + NANCH + 2 * w] = 0;  // pad cols
    }
}

// --------------------------------------------------------------------------
// 128x128 / BK=32 / 4-wave (2x2) depth-2 counted-vmcnt template, 32KB LDS
// -> 5 blocks/CU (explicit launch_bounds(256,5); LDS 160/32 = 5 exact).
// R7->R9 measured law: staging throughput scales with resident blocks
// (5.2 -> 10.3 -> ~13.5 B/cyc/CU at 1/2/4-5); this adds the 5th.
// Chunk-XOR swizzle (counter-verified 0 conflicts since R3).
// --------------------------------------------------------------------------

// ============ scores+exp MFMA: E[r][m+(m>=n)] = bf16(exp(pf·attn_w^T + attn_b)) ============
// exp without max-subtraction is safe: scores sigma ~= 0.06 (pf~0.23 x w~0.01 x K=640).
__global__ __launch_bounds__(256, 5) void scores_mfma_k(
    const ushort_t* __restrict__ A,   // pf16 [M_][640]
    const ushort_t* __restrict__ Bw,  // attnw16 [2816][640]
    const float* __restrict__ attn_b,
    ushort_t* __restrict__ E)         // E [M_+32][2816], unnormalized exp bf16
{
    __shared__ __align__(16) ushort_t As[2][4096];
    __shared__ __align__(16) ushort_t Bs[2][4096];
    // grid 3828 = 174 rowslabs x 22 colslabs; bijective XCD chunk (q=478,r=4)
    const int orig = blockIdx.x;
    const int xcd = orig & 7, pos = orig >> 3;
    const int start = (xcd < 4) ? xcd * 479 : 1916 + (xcd - 4) * 478;
    const int idx = start + pos;
    const int rowb = idx / 22, colb = idx - rowb * 22;
    const int row0 = rowb * 128, col0 = colb * 128;
    const int t = threadIdx.x;
    const int wid = t >> 6, lane = t & 63;
    const int wr = wid >> 1, wc = wid & 1;          // 2x2 wave grid, 64x64 each
    const int srow = lane >> 2;                      // 16 rows per gload
    const int swk  = (((lane & 3) ^ ((lane >> 3) & 3)) * 8);
    const ushort_t* gA = A  + (size_t)(row0 + wid * 32 + srow) * D_ + swk;
    const ushort_t* gB = Bw + (size_t)(col0 + wid * 32 + srow) * D_ + swk;
    f32x4 acc[4][4];
#pragma unroll
    for (int i = 0; i < 4; ++i)
#pragma unroll
        for (int j = 0; j < 4; ++j) acc[i][j] = (f32x4){0.f, 0.f, 0.f, 0.f};
    const int cl = lane & 15, q = lane >> 4;
    const int ra = wr * 64 + cl, rb = wc * 64 + cl;
    const int aoff = ra * 32 + ((q ^ ((ra >> 1) & 3)) * 8);
    const int boff = rb * 32 + ((q ^ ((rb >> 1) & 3)) * 8);

    auto STAGE = [&](int buf, int k0) {
        ushort_t* la = &As[buf][wid * 1024];
        ushort_t* lb = &Bs[buf][wid * 1024];
        gload16(gA + k0, la);
        gload16(gA + k0 + 16 * D_, la + 512);
        gload16(gB + k0, lb);
        gload16(gB + k0 + 16 * D_, lb + 512);
    };
    auto COMPUTE = [&](int buf) {
        short8 af[4], bv[4];
#pragma unroll
        for (int i = 0; i < 4; ++i) af[i] = *(const short8*)&As[buf][aoff + i * 512];
#pragma unroll
        for (int j = 0; j < 4; ++j) bv[j] = *(const short8*)&Bs[buf][boff + j * 512];
        __builtin_amdgcn_s_setprio(1);
#pragma unroll
        for (int i = 0; i < 4; ++i)
#pragma unroll
            for (int j = 0; j < 4; ++j)
                acc[i][j] = __builtin_amdgcn_mfma_f32_16x16x32_bf16(af[i], bv[j], acc[i][j], 0, 0, 0);
        __builtin_amdgcn_s_setprio(0);
    };

    const int NT = D_ / 32;                 // 20
    STAGE(0, 0); STAGE(1, 32);
    int cur = 0;
    for (int tl = 0; tl < NT - 1; ++tl) {
        VMCNT(4); S_BARRIER();              // tile tl landed; tl+1 (4 loads) in flight
        COMPUTE(cur);
        S_BARRIER();
        if (tl + 2 < NT) STAGE(cur, (tl + 2) * 32);
        cur ^= 1;
    }
    VMCNT(0); S_BARRIER();
    COMPUTE(cur);

#pragma unroll
    for (int i = 0; i < 4; ++i) {
#pragma unroll
        for (int ee = 0; ee < 4; ++ee) {
            int r = row0 + wr * 64 + i * 16 + q * 4 + ee;
            int n = r % NANCH;
            ushort_t* orow = E + (size_t)r * NANCHP;
#pragma unroll
            for (int j = 0; j < 4; ++j) {
                int m = col0 + wc * 64 + j * 16 + cl;
                if (m < NM) orow[m + (m >= n)] = f2bf(__expf(acc[i][j][ee] + attn_b[m]));
            }
        }
    }
}

// ============ normalize (vectorized, G13): attn[r][:] = E/sum (fp32); rsum[r] = sum ============
__global__ __launch_bounds__(256) void normalize_k(const ushort_t* __restrict__ E,
    float* __restrict__ attn, float* __restrict__ rsum)
{
    const int r = blockIdx.x;
    float* row = attn + (size_t)r * NANCH;
    const ushort_t* row16 = E + (size_t)r * NANCHP;
    const int t = threadIdx.x;
    __shared__ float red[4];
    float vals[16];                           // static-indexed -> VGPRs
    float s = 0.f;
#pragma unroll
    for (int i = 0; i < 2; ++i) {             // 348 short8-chunks per row (2784 = 348*8)
        int c = t + i * 256;
        float v0 = 0.f, v1 = 0.f, v2 = 0.f, v3 = 0.f, v4 = 0.f, v5 = 0.f, v6 = 0.f, v7 = 0.f;
        if (c < 348) {
            u32x4 u = *(const u32x4*)&row16[8 * c];   // 16B load: 8 bf16
            v0 = bf2f((ushort_t)(u.x & 0xffffu)); v1 = bf2f((ushort_t)(u.x >> 16));
            v2 = bf2f((ushort_t)(u.y & 0xffffu)); v3 = bf2f((ushort_t)(u.y >> 16));
            v4 = bf2f((ushort_t)(u.z & 0xffffu)); v5 = bf2f((ushort_t)(u.z >> 16));
            v6 = bf2f((ushort_t)(u.w & 0xffffu)); v7 = bf2f((ushort_t)(u.w >> 16));
        }
        vals[8 * i + 0] = v0; vals[8 * i + 1] = v1; vals[8 * i + 2] = v2; vals[8 * i + 3] = v3;
        vals[8 * i + 4] = v4; vals[8 * i + 5] = v5; vals[8 * i + 6] = v6; vals[8 * i + 7] = v7;
        s += ((v0 + v1) + (v2 + v3)) + ((v4 + v5) + (v6 + v7));
    }
    for (int off = 32; off; off >>= 1) s += __shfl_down(s, off);
    if ((t & 63) == 0) red[t >> 6] = s;
    __syncthreads();
    s = red[0] + red[1] + red[2] + red[3];
    float inv = 1.0f / s;
    if (t == 0) rsum[r] = s;
#pragma unroll
    for (int i = 0; i < 2; ++i) {
        int c = t + i * 256;
        if (c < 348) {
            float4 w0 = make_float4(vals[8 * i] * inv, vals[8 * i + 1] * inv,
                                    vals[8 * i + 2] * inv, vals[8 * i + 3] * inv);
            float4 w1 = make_float4(vals[8 * i + 4] * inv, vals[8 * i + 5] * inv,
                                    vals[8 * i + 6] * inv, vals[8 * i + 7] * inv);
            *(float4*)&row[8 * c]     = w0;   // 32B stores, 16B-aligned (row%16==0)
            *(float4*)&row[8 * c + 4] = w1;
        }
    }
}

// ============ Gt[b][o][n] = (pf·W1^T)[n][o]  (W1 = hw16 cols 0..639) ============
__global__ __launch_bounds__(256, 2) void gx_mfma_k(
    const ushort_t* __restrict__ A,   // pf16 [M_][640]
    const ushort_t* __restrict__ W,   // hw16 [128][1280]
    ushort_t* __restrict__ Gt)        // [B][128][2816]
{
    __shared__ __align__(16) ushort_t As[2][8192];
    __shared__ __align__(16) ushort_t Bs[2][8192];
    const int t = threadIdx.x;
    const int wid = t >> 6, lane = t & 63;
    const int wr = wid >> 1, wc = wid & 1;          // 2x2 wave grid
    const int row0 = blockIdx.x * 128;
    const int r8 = lane >> 3;
    const int ck = (lane & 7) ^ r8;
    const ushort_t* gA = A + (size_t)(row0 + wid * 8 + r8) * D_ + ck * 8;
    const ushort_t* gB = W + (size_t)(wid * 8 + r8) * D2 + ck * 8;
    f32x4 acc[4][4];
#pragma unroll
    for (int i = 0; i < 4; ++i)
#pragma unroll
        for (int j = 0; j < 4; ++j) acc[i][j] = (f32x4){0.f, 0.f, 0.f, 0.f};
    const int cl = lane & 15, q = lane >> 4, cl7 = lane & 7;

    auto STAGE = [&](int buf, int k0) {
        ushort_t* la = &As[buf][wid * 512];
        ushort_t* lb = &Bs[buf][wid * 512];
#pragma unroll
        for (int j = 0; j < 4; ++j) {
            gload16(gA + k0 + (size_t)j * 32 * D_, la + j * 2048);
            gload16(gB + k0 + (size_t)j * 32 * D2, lb + j * 2048);
        }
    };
    auto COMPUTE = [&](int buf) {
#pragma unroll
        for (int ks = 0; ks < 2; ++ks) {
            short8 af[4], bv[4];
            const int co = ((ks * 4 + q) ^ cl7) * 8;
#pragma unroll
            for (int i = 0; i < 4; ++i)
                af[i] = *(const short8*)&As[buf][(wr * 64 + i * 16 + cl) * 64 + co];
#pragma unroll
            for (int j = 0; j < 4; ++j)
                bv[j] = *(const short8*)&Bs[buf][(wc * 64 + j * 16 + cl) * 64 + co];
            __builtin_amdgcn_s_setprio(1);
#pragma unroll
            for (int i = 0; i < 4; ++i)
#pragma unroll
                for (int j = 0; j < 4; ++j)
                    acc[i][j] = __builtin_amdgcn_mfma_f32_16x16x32_bf16(af[i], bv[j], acc[i][j], 0, 0, 0);
            __builtin_amdgcn_s_setprio(0);
        }
    };

    const int NT = D_ / 64;                 // 10
    STAGE(0, 0); STAGE(1, 64);
    int cur = 0;
    for (int tl = 0; tl < NT - 1; ++tl) {
        VMCNT(8); S_BARRIER();
        COMPUTE(cur);
        S_BARRIER();
        if (tl + 2 < NT) STAGE(cur, (tl + 2) * 64);
        cur ^= 1;
    }
    VMCNT(0); S_BARRIER();
    COMPUTE(cur);

#pragma unroll
    for (int i = 0; i < 4; ++i) {
#pragma unroll
        for (int ee = 0; ee < 4; ++ee) {
            int r = row0 + wr * 64 + i * 16 + q * 4 + ee;   // < M_ (174*128 exact)
            int b = r / NANCH, nl = r - b * NANCH;
#pragma unroll
            for (int j = 0; j < 4; ++j) {
                int o = wc * 64 + j * 16 + cl;
                Gt[((size_t)b * NO + o) * NANCHP + nl] = f2bf(acc[i][j][ee]);
            }
        }
    }
}

// ============ final (split-K x5, BK=32): kc 0..3 = E·G1 (22 tiles each), kc 4 = pf·W2^T (20) ============
__global__ __launch_bounds__(256, 5) void final_mfma_k(
    const ushort_t* __restrict__ E16,  // E [M_+32][2816] (unnormalized exp)
    const ushort_t* __restrict__ pf16, // [M_][640]
    const ushort_t* __restrict__ Gt,   // [B][128][2816]
    const ushort_t* __restrict__ W,    // hw16 [128][1280] (W2 = cols 640..1279)
    float* __restrict__ part)          // [5][M_][128] fp32 partials
{
    __shared__ __align__(16) ushort_t As[2][4096];
    __shared__ __align__(16) ushort_t Bs[2][4096];
    // grid 880: b=XCD (Gt[b] L2-resident), rb=row-slab 0..21, kc=chunk 0..4
    const int b = blockIdx.x & 7;
    const int u = blockIdx.x >> 3;
    const int rb = u % 22, kc = u / 22;
    // BK=32 tiles: E·G1 = tiles [0,88); pf·W2 = tiles [88,108)
    const int g0 = (kc < 4) ? kc * 22 : 88;
    const int NT = (kc < 4) ? 22 : 20;
    const int t = threadIdx.x;
    const int wid = t >> 6, lane = t & 63;
    const int wr = wid >> 1, wc = wid & 1;
    const int srow = lane >> 2;
    const int swk  = (((lane & 3) ^ ((lane >> 3) & 3)) * 8);
    // A rows may over-read past batch end (next batch / +32-row pad; pf16
    // over-read lands in aw16) -> row-independent garbage, discarded at write.
    const size_t arow = (size_t)b * NANCH + rb * 128 + wid * 32 + srow;
    const ushort_t* gAa = E16  + arow * NANCHP + swk;
    const ushort_t* gAp = pf16 + arow * D_ + swk;
    const ushort_t* gBg = Gt + ((size_t)b * NO + wid * 32 + srow) * NANCHP + swk;
    const ushort_t* gBw = W + (size_t)(wid * 32 + srow) * D2 + D_ + swk;
    f32x4 acc[4][4];
#pragma unroll
    for (int i = 0; i < 4; ++i)
#pragma unroll
        for (int j = 0; j < 4; ++j) acc[i][j] = (f32x4){0.f, 0.f, 0.f, 0.f};
    const int cl = lane & 15, q = lane >> 4;
    const int ra = wr * 64 + cl, rbb = wc * 64 + cl;
    const int aoff = ra * 32 + ((q ^ ((ra >> 1) & 3)) * 8);
    const int boff = rbb * 32 + ((q ^ ((rbb >> 1) & 3)) * 8);

    auto STAGE = [&](int buf, int gt) {     // gt = global K-tile index
        ushort_t* la = &As[buf][wid * 1024];
        ushort_t* lb = &Bs[buf][wid * 1024];
        if (gt < 88) {
            const int k0 = gt * 32;
            gload16(gAa + k0, la);
            gload16(gAa + k0 + (size_t)16 * NANCHP, la + 512);
            gload16(gBg + k0, lb);
            gload16(gBg + k0 + (size_t)16 * NANCHP, lb + 512);
        } else {
            const int kk = (gt - 88) * 32;
            gload16(gAp + kk, la);
            gload16(gAp + kk + (size_t)16 * D_, la + 512);
            gload16(gBw + kk, lb);
            gload16(gBw + kk + (size_t)16 * D2, lb + 512);
        }
    };
    auto COMPUTE = [&](int buf) {
        short8 af[4], bv[4];
#pragma unroll
        for (int i = 0; i < 4; ++i) af[i] = *(const short8*)&As[buf][aoff + i * 512];
#pragma unroll
        for (int j = 0; j < 4; ++j) bv[j] = *(const short8*)&Bs[buf][boff + j * 512];
        __builtin_amdgcn_s_setprio(1);
#pragma unroll
        for (int i = 0; i < 4; ++i)
#pragma unroll
            for (int j = 0; j < 4; ++j)
                acc[i][j] = __builtin_amdgcn_mfma_f32_16x16x32_bf16(af[i], bv[j], acc[i][j], 0, 0, 0);
        __builtin_amdgcn_s_setprio(0);
    };

    STAGE(0, g0); STAGE(1, g0 + 1);
    int cur = 0;
    for (int tl = 0; tl < NT - 1; ++tl) {
        VMCNT(4); S_BARRIER();
        COMPUTE(cur);
        S_BARRIER();
        if (tl + 2 < NT) STAGE(cur, g0 + tl + 2);
        cur ^= 1;
    }
    VMCNT(0); S_BARRIER();
    COMPUTE(cur);

    float* pout = part + (size_t)kc * M_ * NO;
#pragma unroll
    for (int i = 0; i < 4; ++i) {
#pragma unroll
        for (int ee = 0; ee < 4; ++ee) {
            int nl = rb * 128 + wr * 64 + i * 16 + q * 4 + ee;
            if (nl < NANCH) {
                int r = b * NANCH + nl;
#pragma unroll
                for (int j = 0; j < 4; ++j) {
                    int oo = wc * 64 + j * 16 + cl;
                    pout[(size_t)r * NO + oo] = acc[i][j][ee];
                }
            }
        }
    }
}

// ============ reduce: out = (p0+p1+p2+p3)/rsum + p4 + bias; heads epilogue ============
__global__ __launch_bounds__(256) void reduce_heads_k(
    const float* __restrict__ part,    // [5][M_][128]
    const float* __restrict__ rsum,
    const float* __restrict__ cls_b, const float* __restrict__ reg_b,
    const float* __restrict__ anchors,
    float* __restrict__ cls_out, float* __restrict__ lanes)
{
    int t = blockIdx.x * 256 + threadIdx.x;
    if (t >= M_ * 80) return;
    int r = t / 80, oo = t - r * 80;
    int nl = r % NANCH;
    if (oo < 75) {
        float inv = 1.0f / rsum[r];
        size_t base = (size_t)r * NO + oo, st = (size_t)M_ * NO;
        float v = ((part[base] + part[base + st]) + (part[base + 2 * st] + part[base + 3 * st])) * inv
                + part[base + 4 * st];
        if (oo < 2) {
            cls_out[(size_t)r * 2 + oo] = v + cls_b[oo];
        } else {
            int qq = oo - 2;
            int c = 4 + qq;
            float res = v + reg_b[qq];
            if (qq > 0) res += anchors[(size_t)nl * ALEN + c];
            lanes[(size_t)r * ALEN + c] = res;
        }
    } else if (oo < 79) {
        int c = oo - 75;                      // lanes cols 0..3 = anchors
        lanes[(size_t)r * ALEN + c] = anchors[(size_t)nl * ALEN + c];
    }
}

extern "C" void kernel_launch(void* const* d_in, const int* in_sizes, int n_in,
                              void* d_out, int out_size, void* d_ws, size_t ws_size,
                              hipStream_t stream)
{
    (void)in_sizes; (void)n_in; (void)out_size; (void)ws_size;
    const float* x       = (const float*)d_in[0];
    const float* conv_w  = (const float*)d_in[1];
    const float* conv_b  = (const float*)d_in[2];
    const float* attn_w  = (const float*)d_in[3];
    const float* attn_b  = (const float*)d_in[4];
    const float* cls_w   = (const float*)d_in[5];
    const float* cls_b   = (const float*)d_in[6];
    const float* reg_w   = (const float*)d_in[7];
    const float* reg_b   = (const float*)d_in[8];
    const float* anchors = (const float*)d_in[9];
    const int*   cut_xs  = (const int*)d_in[10];
    const unsigned char* invalid = (const unsigned char*)d_in[11];

    float* out     = (float*)d_out;
    float* cls_out = out;
    float* lanes   = out + (size_t)M_ * 2;
    float* attn    = out + (size_t)M_ * 2 + (size_t)M_ * ALEN;

    // workspace layout (~222 MB)
    char* w = (char*)d_ws;
    float* feat      = (float*)w;    w += (size_t)B_ * CF * HFM * WFM * 4;       // 512 KB
    ushort_t* pf16   = (ushort_t*)w; w += (size_t)M_ * D_ * 2;                   // 28.5 MB
    ushort_t* aw16   = (ushort_t*)w; w += (size_t)NMPAD * D_ * 2;                // 3.6 MB (absorbs pf16 over-read)
    ushort_t* hw16   = (ushort_t*)w; w += (size_t)128 * D2 * 2;                  // 320 KB
    ushort_t* Gt     = (ushort_t*)w; w += (size_t)B_ * NO * NANCHP * 2;          // 5.8 MB
    float* part      = (float*)w;    w += (size_t)5 * M_ * NO * 4;               // 57 MB
    float* rsum      = (float*)w;    w += (size_t)M_ * 4;                        // 89 KB
    ushort_t* E16    = (ushort_t*)w; w += (size_t)(M_ + 32) * NANCHP * 2;        // 125.6 MB

    conv_feat_k<<<(B_ * CF * HFM * WFM + 255) / 256, 256, 0, stream>>>(x, conv_w, conv_b, feat);
    gather_pf_k<<<(int)(((long long)M_ * D_ + 255) / 256), 256, 0, stream>>>(feat, cut_xs, invalid, pf16);
    prep_attn_w_k<<<(NMPAD * D_ + 255) / 256, 256, 0, stream>>>(attn_w, aw16);
    prep_heads_w_k<<<(128 * D2 + 255) / 256, 256, 0, stream>>>(cls_w, reg_w, hw16);

    gx_mfma_k<<<M_ / 128, 256, 0, stream>>>(pf16, hw16, Gt);
    zero_gtpad_k<<<(B_ * NO * 32 + 255) / 256, 256, 0, stream>>>(Gt);
    zero_epad_k<<<(M_ * 17 + 255) / 256, 256, 0, stream>>>(E16);

    scores_mfma_k<<<dim3(174 * 22), 256, 0, stream>>>(pf16, aw16, attn_b, E16);
    normalize_k<<<M_, 256, 0, stream>>>(E16, attn, rsum);

    final_mfma_k<<<dim3(5 * 22 * B_), 256, 0, stream>>>(E16, pf16, Gt, hw16, part);
    reduce_heads_k<<<(M_ * 80 + 255) / 256, 256, 0, stream>>>(part, rsum, cls_b, reg_b,
                                                              anchors, cls_out, lanes);
}

// Round 11
// 413.456 us; speedup vs baseline: 1.7915x; 1.7915x over previous
//
#include <hip/hip_runtime.h>

typedef unsigned short ushort_t;
typedef unsigned int   uint32;
typedef __attribute__((ext_vector_type(8))) short short8;   // 8 bf16 (4 VGPRs)
typedef __attribute__((ext_vector_type(4))) float f32x4;    // MFMA acc
typedef __attribute__((ext_vector_type(4))) uint32 u32x4;

// ---------------- problem constants ----------------
#define B_     8
#define CIN    512
#define HFM    10
#define WFM    25
#define CF     64
#define NANCH  2784          // N
#define NANCHP 2816          // N padded to 64 (K-tiling)
#define NM     2783          // N-1
#define NMPAD  2816          // N-1 padded (cols for scores)
#define D_     640           // CF*HFM
#define D2     1280
#define ALEN   77
#define M_     (B_*NANCH)    // 22272
#define NO     128           // padded head-output dim (75 used)

#define VMCNT(N)   asm volatile("s_waitcnt vmcnt(" #N ")" ::: "memory")
#define S_BARRIER() do { __builtin_amdgcn_s_barrier(); __builtin_amdgcn_sched_barrier(0); } while (0)

__device__ __forceinline__ ushort_t f2bf(float f) {
    uint32 u = __float_as_uint(f);
    u += 0x7fffu + ((u >> 16) & 1u);     // RNE
    return (ushort_t)(u >> 16);
}
__device__ __forceinline__ float bf2f(ushort_t h) {
    return __uint_as_float(((uint32)h) << 16);
}

__device__ __forceinline__ void gload16(const ushort_t* g, ushort_t* l) {
    __builtin_amdgcn_global_load_lds(
        (const __attribute__((address_space(1))) void*)g,
        (__attribute__((address_space(3))) void*)l, 16, 0, 0);
}

// ============ 1x1 conv ============
__global__ __launch_bounds__(256) void conv_feat_k(const float* __restrict__ x,
    const float* __restrict__ w, const float* __restrict__ bias,
    float* __restrict__ feat)
{
    int t = blockIdx.x * 256 + threadIdx.x;
    if (t >= B_ * CF * HFM * WFM) return;
    int pos = t % (HFM * WFM);
    int f   = (t / (HFM * WFM)) % CF;
    int b   = t / (CF * HFM * WFM);
    const float* xp = x + (size_t)b * CIN * HFM * WFM + pos;
    const float* wp = w + (size_t)f * CIN;
    float s = bias[f];
#pragma unroll 4
    for (int c = 0; c < CIN; ++c)
        s += xp[(size_t)c * (HFM * WFM)] * wp[c];
    feat[t] = s;
}

// ============ gather -> pf16 [M_][640] ============
__global__ __launch_bounds__(256) void gather_pf_k(const float* __restrict__ feat,
    const int* __restrict__ cut_xs, const unsigned char* __restrict__ invalid,
    ushort_t* __restrict__ pf16)
{
    long long t = (long long)blockIdx.x * 256 + threadIdx.x;
    if (t >= (long long)M_ * D_) return;
    int d = (int)(t % D_);
    int r = (int)(t / D_);
    int n = r % NANCH;
    int b = r / NANCH;
    int f = d / HFM, h = d - f * HFM;
    int idx = n * HFM + h;
    float v = 0.f;
    if (!invalid[idx]) {
        int xs = cut_xs[idx];
        v = feat[((size_t)(b * CF + f) * HFM + h) * WFM + xs];
    }
    pf16[t] = f2bf(v);
}

// ============ attn_w fp32 [2783][640] -> bf16 padded [2816][640] ============
__global__ __launch_bounds__(256) void prep_attn_w_k(const float* __restrict__ attn_w,
    ushort_t* __restrict__ w16)
{
    int t = blockIdx.x * 256 + threadIdx.x;
    if (t >= NMPAD * D_) return;
    int m = t / D_;
    w16[t] = (m < NM) ? f2bf(attn_w[(size_t)m * D_ + (t % D_)]) : (ushort_t)0;
}

// ============ heads weights -> bf16 padded [128][1280] ============
__global__ __launch_bounds__(256) void prep_heads_w_k(const float* __restrict__ cls_w,
    const float* __restrict__ reg_w, ushort_t* __restrict__ w16)
{
    int t = blockIdx.x * 256 + threadIdx.x;
    if (t >= 128 * D2) return;
    int o = t / D2, k = t % D2;
    float v = 0.f;
    if (o < 2)       v = cls_w[(size_t)o * D2 + k];
    else if (o < 75) v = reg_w[(size_t)(o - 2) * D2 + k];
    w16[t] = (o < 75) ? f2bf(v) : (ushort_t)0;
}

// ============ zero Gt K-pad cols [2784..2816) ============
__global__ __launch_bounds__(256) void zero_gtpad_k(ushort_t* __restrict__ Gt)
{
    int t = blockIdx.x * 256 + threadIdx.x;
    if (t >= B_ * NO * 32) return;
    int n = t & 31, o = (t >> 5) & (NO - 1), b = t >> 12;
    Gt[((size_t)b * NO + o) * NANCHP + NANCH + n] = 0;
}

// ============ zero E diag + K-pad cols (scores never writes these) ============
__global__ __launch_bounds__(256) void zero_epad_k(ushort_t* __restrict__ E)
{
    int t = blockIdx.x * 256 + threadIdx.x;
    if (t < M_) {
        E[(size_t)t * NANCHP + (t % NANCH)] = 0;            // diagonal
    } else if (t < M_ * 17) {
        int idx = t - M_;
        int r = idx >> 4, w = idx & 15;
        *(uint32*)&E[(size_t)r * NANCHP + NANCH + 2 * w] = 0;  // pad cols
    }
}

// --------------------------------------------------------------------------
// 128x128 / BK=32 / 4-wave (2x2) depth-2 counted-vmcnt template, 32KB LDS.
// __launch_bounds__(256,4): VGPR=64, zero spills, 4 blocks/CU.
// R10 LESSON: (256,5) forced VGPR=48 < acc's 64 -> scratch spills
// (WRITE_SIZE 122->793MB, dur 151->368us). Occupancy bought with spills
// is worthless (Guideline 6). 4 blocks + VGPR 64 is this template's optimum.
// Chunk-XOR swizzle (counter-verified 0 conflicts since R3).
// --------------------------------------------------------------------------

// ============ scores+exp MFMA: E[r][m+(m>=n)] = bf16(exp(pf·attn_w^T + attn_b)) ============
// exp without max-subtraction is safe: scores sigma ~= 0.06 (pf~0.23 x w~0.01 x K=640).
__global__ __launch_bounds__(256, 4) void scores_mfma_k(
    const ushort_t* __restrict__ A,   // pf16 [M_][640]
    const ushort_t* __restrict__ Bw,  // attnw16 [2816][640]
    const float* __restrict__ attn_b,
    ushort_t* __restrict__ E)         // E [M_+32][2816], unnormalized exp bf16
{
    __shared__ __align__(16) ushort_t As[2][4096];
    __shared__ __align__(16) ushort_t Bs[2][4096];
    // grid 3828 = 174 rowslabs x 22 colslabs; bijective XCD chunk (q=478,r=4)
    const int orig = blockIdx.x;
    const int xcd = orig & 7, pos = orig >> 3;
    const int start = (xcd < 4) ? xcd * 479 : 1916 + (xcd - 4) * 478;
    const int idx = start + pos;
    const int rowb = idx / 22, colb = idx - rowb * 22;
    const int row0 = rowb * 128, col0 = colb * 128;
    const int t = threadIdx.x;
    const int wid = t >> 6, lane = t & 63;
    const int wr = wid >> 1, wc = wid & 1;          // 2x2 wave grid, 64x64 each
    const int srow = lane >> 2;                      // 16 rows per gload
    const int swk  = (((lane & 3) ^ ((lane >> 3) & 3)) * 8);
    const ushort_t* gA = A  + (size_t)(row0 + wid * 32 + srow) * D_ + swk;
    const ushort_t* gB = Bw + (size_t)(col0 + wid * 32 + srow) * D_ + swk;
    f32x4 acc[4][4];
#pragma unroll
    for (int i = 0; i < 4; ++i)
#pragma unroll
        for (int j = 0; j < 4; ++j) acc[i][j] = (f32x4){0.f, 0.f, 0.f, 0.f};
    const int cl = lane & 15, q = lane >> 4;
    const int ra = wr * 64 + cl, rb = wc * 64 + cl;
    const int aoff = ra * 32 + ((q ^ ((ra >> 1) & 3)) * 8);
    const int boff = rb * 32 + ((q ^ ((rb >> 1) & 3)) * 8);

    auto STAGE = [&](int buf, int k0) {
        ushort_t* la = &As[buf][wid * 1024];
        ushort_t* lb = &Bs[buf][wid * 1024];
        gload16(gA + k0, la);
        gload16(gA + k0 + 16 * D_, la + 512);
        gload16(gB + k0, lb);
        gload16(gB + k0 + 16 * D_, lb + 512);
    };
    auto COMPUTE = [&](int buf) {
        short8 af[4], bv[4];
#pragma unroll
        for (int i = 0; i < 4; ++i) af[i] = *(const short8*)&As[buf][aoff + i * 512];
#pragma unroll
        for (int j = 0; j < 4; ++j) bv[j] = *(const short8*)&Bs[buf][boff + j * 512];
        __builtin_amdgcn_s_setprio(1);
#pragma unroll
        for (int i = 0; i < 4; ++i)
#pragma unroll
            for (int j = 0; j < 4; ++j)
                acc[i][j] = __builtin_amdgcn_mfma_f32_16x16x32_bf16(af[i], bv[j], acc[i][j], 0, 0, 0);
        __builtin_amdgcn_s_setprio(0);
    };

    const int NT = D_ / 32;                 // 20
    STAGE(0, 0); STAGE(1, 32);
    int cur = 0;
    for (int tl = 0; tl < NT - 1; ++tl) {
        VMCNT(4); S_BARRIER();              // tile tl landed; tl+1 (4 loads) in flight
        COMPUTE(cur);
        S_BARRIER();
        if (tl + 2 < NT) STAGE(cur, (tl + 2) * 32);
        cur ^= 1;
    }
    VMCNT(0); S_BARRIER();
    COMPUTE(cur);

#pragma unroll
    for (int i = 0; i < 4; ++i) {
#pragma unroll
        for (int ee = 0; ee < 4; ++ee) {
            int r = row0 + wr * 64 + i * 16 + q * 4 + ee;
            int n = r % NANCH;
            ushort_t* orow = E + (size_t)r * NANCHP;
#pragma unroll
            for (int j = 0; j < 4; ++j) {
                int m = col0 + wc * 64 + j * 16 + cl;
                if (m < NM) orow[m + (m >= n)] = f2bf(__expf(acc[i][j][ee] + attn_b[m]));
            }
        }
    }
}

// ============ normalize (vectorized, G13): attn[r][:] = E/sum (fp32); rsum[r] = sum ============
__global__ __launch_bounds__(256) void normalize_k(const ushort_t* __restrict__ E,
    float* __restrict__ attn, float* __restrict__ rsum)
{
    const int r = blockIdx.x;
    float* row = attn + (size_t)r * NANCH;
    const ushort_t* row16 = E + (size_t)r * NANCHP;
    const int t = threadIdx.x;
    __shared__ float red[4];
    float vals[16];                           // static-indexed -> VGPRs
    float s = 0.f;
#pragma unroll
    for (int i = 0; i < 2; ++i) {             // 348 short8-chunks per row (2784 = 348*8)
        int c = t + i * 256;
        float v0 = 0.f, v1 = 0.f, v2 = 0.f, v3 = 0.f, v4 = 0.f, v5 = 0.f, v6 = 0.f, v7 = 0.f;
        if (c < 348) {
            u32x4 u = *(const u32x4*)&row16[8 * c];   // 16B load: 8 bf16
            v0 = bf2f((ushort_t)(u.x & 0xffffu)); v1 = bf2f((ushort_t)(u.x >> 16));
            v2 = bf2f((ushort_t)(u.y & 0xffffu)); v3 = bf2f((ushort_t)(u.y >> 16));
            v4 = bf2f((ushort_t)(u.z & 0xffffu)); v5 = bf2f((ushort_t)(u.z >> 16));
            v6 = bf2f((ushort_t)(u.w & 0xffffu)); v7 = bf2f((ushort_t)(u.w >> 16));
        }
        vals[8 * i + 0] = v0; vals[8 * i + 1] = v1; vals[8 * i + 2] = v2; vals[8 * i + 3] = v3;
        vals[8 * i + 4] = v4; vals[8 * i + 5] = v5; vals[8 * i + 6] = v6; vals[8 * i + 7] = v7;
        s += ((v0 + v1) + (v2 + v3)) + ((v4 + v5) + (v6 + v7));
    }
    for (int off = 32; off; off >>= 1) s += __shfl_down(s, off);
    if ((t & 63) == 0) red[t >> 6] = s;
    __syncthreads();
    s = red[0] + red[1] + red[2] + red[3];
    float inv = 1.0f / s;
    if (t == 0) rsum[r] = s;
#pragma unroll
    for (int i = 0; i < 2; ++i) {
        int c = t + i * 256;
        if (c < 348) {
            float4 w0 = make_float4(vals[8 * i] * inv, vals[8 * i + 1] * inv,
                                    vals[8 * i + 2] * inv, vals[8 * i + 3] * inv);
            float4 w1 = make_float4(vals[8 * i + 4] * inv, vals[8 * i + 5] * inv,
                                    vals[8 * i + 6] * inv, vals[8 * i + 7] * inv);
            *(float4*)&row[8 * c]     = w0;   // 32B stores, 16B-aligned
            *(float4*)&row[8 * c + 4] = w1;
        }
    }
}

// ============ Gt[b][o][n] = (pf·W1^T)[n][o]  (W1 = hw16 cols 0..639) ============
__global__ __launch_bounds__(256, 2) void gx_mfma_k(
    const ushort_t* __restrict__ A,   // pf16 [M_][640]
    const ushort_t* __restrict__ W,   // hw16 [128][1280]
    ushort_t* __restrict__ Gt)        // [B][128][2816]
{
    __shared__ __align__(16) ushort_t As[2][8192];
    __shared__ __align__(16) ushort_t Bs[2][8192];
    const int t = threadIdx.x;
    const int wid = t >> 6, lane = t & 63;
    const int wr = wid >> 1, wc = wid & 1;          // 2x2 wave grid
    const int row0 = blockIdx.x * 128;
    const int r8 = lane >> 3;
    const int ck = (lane & 7) ^ r8;
    const ushort_t* gA = A + (size_t)(row0 + wid * 8 + r8) * D_ + ck * 8;
    const ushort_t* gB = W + (size_t)(wid * 8 + r8) * D2 + ck * 8;
    f32x4 acc[4][4];
#pragma unroll
    for (int i = 0; i < 4; ++i)
#pragma unroll
        for (int j = 0; j < 4; ++j) acc[i][j] = (f32x4){0.f, 0.f, 0.f, 0.f};
    const int cl = lane & 15, q = lane >> 4, cl7 = lane & 7;

    auto STAGE = [&](int buf, int k0) {
        ushort_t* la = &As[buf][wid * 512];
        ushort_t* lb = &Bs[buf][wid * 512];
#pragma unroll
        for (int j = 0; j < 4; ++j) {
            gload16(gA + k0 + (size_t)j * 32 * D_, la + j * 2048);
            gload16(gB + k0 + (size_t)j * 32 * D2, lb + j * 2048);
        }
    };
    auto COMPUTE = [&](int buf) {
#pragma unroll
        for (int ks = 0; ks < 2; ++ks) {
            short8 af[4], bv[4];
            const int co = ((ks * 4 + q) ^ cl7) * 8;
#pragma unroll
            for (int i = 0; i < 4; ++i)
                af[i] = *(const short8*)&As[buf][(wr * 64 + i * 16 + cl) * 64 + co];
#pragma unroll
            for (int j = 0; j < 4; ++j)
                bv[j] = *(const short8*)&Bs[buf][(wc * 64 + j * 16 + cl) * 64 + co];
            __builtin_amdgcn_s_setprio(1);
#pragma unroll
            for (int i = 0; i < 4; ++i)
#pragma unroll
                for (int j = 0; j < 4; ++j)
                    acc[i][j] = __builtin_amdgcn_mfma_f32_16x16x32_bf16(af[i], bv[j], acc[i][j], 0, 0, 0);
            __builtin_amdgcn_s_setprio(0);
        }
    };

    const int NT = D_ / 64;                 // 10
    STAGE(0, 0); STAGE(1, 64);
    int cur = 0;
    for (int tl = 0; tl < NT - 1; ++tl) {
        VMCNT(8); S_BARRIER();
        COMPUTE(cur);
        S_BARRIER();
        if (tl + 2 < NT) STAGE(cur, (tl + 2) * 64);
        cur ^= 1;
    }
    VMCNT(0); S_BARRIER();
    COMPUTE(cur);

#pragma unroll
    for (int i = 0; i < 4; ++i) {
#pragma unroll
        for (int ee = 0; ee < 4; ++ee) {
            int r = row0 + wr * 64 + i * 16 + q * 4 + ee;   // < M_ (174*128 exact)
            int b = r / NANCH, nl = r - b * NANCH;
#pragma unroll
            for (int j = 0; j < 4; ++j) {
                int o = wc * 64 + j * 16 + cl;
                Gt[((size_t)b * NO + o) * NANCHP + nl] = f2bf(acc[i][j][ee]);
            }
        }
    }
}

// ============ final (split-K x5, BK=32): kc 0..3 = E·G1 (22 tiles each), kc 4 = pf·W2^T (20) ============
__global__ __launch_bounds__(256, 4) void final_mfma_k(
    const ushort_t* __restrict__ E16,  // E [M_+32][2816] (unnormalized exp)
    const ushort_t* __restrict__ pf16, // [M_][640]
    const ushort_t* __restrict__ Gt,   // [B][128][2816]
    const ushort_t* __restrict__ W,    // hw16 [128][1280] (W2 = cols 640..1279)
    float* __restrict__ part)          // [5][M_][128] fp32 partials
{
    __shared__ __align__(16) ushort_t As[2][4096];
    __shared__ __align__(16) ushort_t Bs[2][4096];
    // grid 880: b=XCD (Gt[b] L2-resident), rb=row-slab 0..21, kc=chunk 0..4
    const int b = blockIdx.x & 7;
    const int u = blockIdx.x >> 3;
    const int rb = u % 22, kc = u / 22;
    // BK=32 tiles: E·G1 = tiles [0,88); pf·W2 = tiles [88,108)
    const int g0 = (kc < 4) ? kc * 22 : 88;
    const int NT = (kc < 4) ? 22 : 20;
    const int t = threadIdx.x;
    const int wid = t >> 6, lane = t & 63;
    const int wr = wid >> 1, wc = wid & 1;
    const int srow = lane >> 2;
    const int swk  = (((lane & 3) ^ ((lane >> 3) & 3)) * 8);
    // A rows may over-read past batch end (next batch / +32-row pad; pf16
    // over-read lands in aw16) -> row-independent garbage, discarded at write.
    const size_t arow = (size_t)b * NANCH + rb * 128 + wid * 32 + srow;
    const ushort_t* gAa = E16  + arow * NANCHP + swk;
    const ushort_t* gAp = pf16 + arow * D_ + swk;
    const ushort_t* gBg = Gt + ((size_t)b * NO + wid * 32 + srow) * NANCHP + swk;
    const ushort_t* gBw = W + (size_t)(wid * 32 + srow) * D2 + D_ + swk;
    f32x4 acc[4][4];
#pragma unroll
    for (int i = 0; i < 4; ++i)
#pragma unroll
        for (int j = 0; j < 4; ++j) acc[i][j] = (f32x4){0.f, 0.f, 0.f, 0.f};
    const int cl = lane & 15, q = lane >> 4;
    const int ra = wr * 64 + cl, rbb = wc * 64 + cl;
    const int aoff = ra * 32 + ((q ^ ((ra >> 1) & 3)) * 8);
    const int boff = rbb * 32 + ((q ^ ((rbb >> 1) & 3)) * 8);

    auto STAGE = [&](int buf, int gt) {     // gt = global K-tile index
        ushort_t* la = &As[buf][wid * 1024];
        ushort_t* lb = &Bs[buf][wid * 1024];
        if (gt < 88) {
            const int k0 = gt * 32;
            gload16(gAa + k0, la);
            gload16(gAa + k0 + (size_t)16 * NANCHP, la + 512);
            gload16(gBg + k0, lb);
            gload16(gBg + k0 + (size_t)16 * NANCHP, lb + 512);
        } else {
            const int kk = (gt - 88) * 32;
            gload16(gAp + kk, la);
            gload16(gAp + kk + (size_t)16 * D_, la + 512);
            gload16(gBw + kk, lb);
            gload16(gBw + kk + (size_t)16 * D2, lb + 512);
        }
    };
    auto COMPUTE = [&](int buf) {
        short8 af[4], bv[4];
#pragma unroll
        for (int i = 0; i < 4; ++i) af[i] = *(const short8*)&As[buf][aoff + i * 512];
#pragma unroll
        for (int j = 0; j < 4; ++j) bv[j] = *(const short8*)&Bs[buf][boff + j * 512];
        __builtin_amdgcn_s_setprio(1);
#pragma unroll
        for (int i = 0; i < 4; ++i)
#pragma unroll
            for (int j = 0; j < 4; ++j)
                acc[i][j] = __builtin_amdgcn_mfma_f32_16x16x32_bf16(af[i], bv[j], acc[i][j], 0, 0, 0);
        __builtin_amdgcn_s_setprio(0);
    };

    STAGE(0, g0); STAGE(1, g0 + 1);
    int cur = 0;
    for (int tl = 0; tl < NT - 1; ++tl) {
        VMCNT(4); S_BARRIER();
        COMPUTE(cur);
        S_BARRIER();
        if (tl + 2 < NT) STAGE(cur, g0 + tl + 2);
        cur ^= 1;
    }
    VMCNT(0); S_BARRIER();
    COMPUTE(cur);

    float* pout = part + (size_t)kc * M_ * NO;
#pragma unroll
    for (int i = 0; i < 4; ++i) {
#pragma unroll
        for (int ee = 0; ee < 4; ++ee) {
            int nl = rb * 128 + wr * 64 + i * 16 + q * 4 + ee;
            if (nl < NANCH) {
                int r = b * NANCH + nl;
#pragma unroll
                for (int j = 0; j < 4; ++j) {
                    int oo = wc * 64 + j * 16 + cl;
                    pout[(size_t)r * NO + oo] = acc[i][j][ee];
                }
            }
        }
    }
}

// ============ reduce: out = (p0+p1+p2+p3)/rsum + p4 + bias; heads epilogue ============
__global__ __launch_bounds__(256) void reduce_heads_k(
    const float* __restrict__ part,    // [5][M_][128]
    const float* __restrict__ rsum,
    const float* __restrict__ cls_b, const float* __restrict__ reg_b,
    const float* __restrict__ anchors,
    float* __restrict__ cls_out, float* __restrict__ lanes)
{
    int t = blockIdx.x * 256 + threadIdx.x;
    if (t >= M_ * 80) return;
    int r = t / 80, oo = t - r * 80;
    int nl = r % NANCH;
    if (oo < 75) {
        float inv = 1.0f / rsum[r];
        size_t base = (size_t)r * NO + oo, st = (size_t)M_ * NO;
        float v = ((part[base] + part[base + st]) + (part[base + 2 * st] + part[base + 3 * st])) * inv
                + part[base + 4 * st];
        if (oo < 2) {
            cls_out[(size_t)r * 2 + oo] = v + cls_b[oo];
        } else {
            int qq = oo - 2;
            int c = 4 + qq;
            float res = v + reg_b[qq];
            if (qq > 0) res += anchors[(size_t)nl * ALEN + c];
            lanes[(size_t)r * ALEN + c] = res;
        }
    } else if (oo < 79) {
        int c = oo - 75;                      // lanes cols 0..3 = anchors
        lanes[(size_t)r * ALEN + c] = anchors[(size_t)nl * ALEN + c];
    }
}

extern "C" void kernel_launch(void* const* d_in, const int* in_sizes, int n_in,
                              void* d_out, int out_size, void* d_ws, size_t ws_size,
                              hipStream_t stream)
{
    (void)in_sizes; (void)n_in; (void)out_size; (void)ws_size;
    const float* x       = (const float*)d_in[0];
    const float* conv_w  = (const float*)d_in[1];
    const float* conv_b  = (const float*)d_in[2];
    const float* attn_w  = (const float*)d_in[3];
    const float* attn_b  = (const float*)d_in[4];
    const float* cls_w   = (const float*)d_in[5];
    const float* cls_b   = (const float*)d_in[6];
    const float* reg_w   = (const float*)d_in[7];
    const float* reg_b   = (const float*)d_in[8];
    const float* anchors = (const float*)d_in[9];
    const int*   cut_xs  = (const int*)d_in[10];
    const unsigned char* invalid = (const unsigned char*)d_in[11];

    float* out     = (float*)d_out;
    float* cls_out = out;
    float* lanes   = out + (size_t)M_ * 2;
    float* attn    = out + (size_t)M_ * 2 + (size_t)M_ * ALEN;

    // workspace layout (~222 MB)
    char* w = (char*)d_ws;
    float* feat      = (float*)w;    w += (size_t)B_ * CF * HFM * WFM * 4;       // 512 KB
    ushort_t* pf16   = (ushort_t*)w; w += (size_t)M_ * D_ * 2;                   // 28.5 MB
    ushort_t* aw16   = (ushort_t*)w; w += (size_t)NMPAD * D_ * 2;                // 3.6 MB (absorbs pf16 over-read)
    ushort_t* hw16   = (ushort_t*)w; w += (size_t)128 * D2 * 2;                  // 320 KB
    ushort_t* Gt     = (ushort_t*)w; w += (size_t)B_ * NO * NANCHP * 2;          // 5.8 MB
    float* part      = (float*)w;    w += (size_t)5 * M_ * NO * 4;               // 57 MB
    float* rsum      = (float*)w;    w += (size_t)M_ * 4;                        // 89 KB
    ushort_t* E16    = (ushort_t*)w; w += (size_t)(M_ + 32) * NANCHP * 2;        // 125.6 MB

    conv_feat_k<<<(B_ * CF * HFM * WFM + 255) / 256, 256, 0, stream>>>(x, conv_w, conv_b, feat);
    gather_pf_k<<<(int)(((long long)M_ * D_ + 255) / 256), 256, 0, stream>>>(feat, cut_xs, invalid, pf16);
    prep_attn_w_k<<<(NMPAD * D_ + 255) / 256, 256, 0, stream>>>(attn_w, aw16);
    prep_heads_w_k<<<(128 * D2 + 255) / 256, 256, 0, stream>>>(cls_w, reg_w, hw16);

    gx_mfma_k<<<M_ / 128, 256, 0, stream>>>(pf16, hw16, Gt);
    zero_gtpad_k<<<(B_ * NO * 32 + 255) / 256, 256, 0, stream>>>(Gt);
    zero_epad_k<<<(M_ * 17 + 255) / 256, 256, 0, stream>>>(E16);

    scores_mfma_k<<<dim3(174 * 22), 256, 0, stream>>>(pf16, aw16, attn_b, E16);
    normalize_k<<<M_, 256, 0, stream>>>(E16, attn, rsum);

    final_mfma_k<<<dim3(5 * 22 * B_), 256, 0, stream>>>(E16, pf16, Gt, hw16, part);
    reduce_heads_k<<<(M_ * 80 + 255) / 256, 256, 0, stream>>>(part, rsum, cls_b, reg_b,
                                                              anchors, cls_out, lanes);
}